// Round 1
// baseline (7246.355 us; speedup 1.0000x reference)
//
#include <hip/hip_runtime.h>
#include <cstdint>

typedef short bf16x8 __attribute__((ext_vector_type(8)));
typedef float f32x4  __attribute__((ext_vector_type(4)));

constexpr int Bn = 16, Tn = 2048, Dn = 512, Hn = 512;
constexpr int NWG = 32;        // j-slice workgroups (16 h-columns each)
constexpr int JT  = Hn / NWG;  // 16
constexpr int NTHREADS = 256;  // 4 waves
constexpr int KW = 128;        // K-range per wave (4 MFMA k-steps of 32)

__device__ __forceinline__ unsigned short f2bf(float f) {
  union { float f; unsigned u; } v; v.f = f;
  unsigned r = v.u + 0x7FFFu + ((v.u >> 16) & 1u);   // RNE
  return (unsigned short)(r >> 16);
}

__global__ __launch_bounds__(NTHREADS, 1) void gru_scan(
    const float* __restrict__ x, const int* __restrict__ start,
    const float* __restrict__ w_ih, const float* __restrict__ w_hh,
    const float* __restrict__ b_ih, const float* __restrict__ b_hh,
    float* __restrict__ out, unsigned short* __restrict__ h_ex,
    unsigned int* __restrict__ counter)
{
  const int tid  = threadIdx.x;
  const int lane = tid & 63;
  const int wv   = tid >> 6;
  const int j0   = blockIdx.x * JT;
  const int kb   = wv * KW;
  const int arow = lane & 15;        // A row (batch) / B col (gate-within-tile)
  const int koff = (lane >> 4) * 8;  // k offset within 32-wide k-step

  // ---- persistent weight B-fragments in registers (bf16) ----
  // gate g: rows g*512 + j0 + arow of W; frag holds W[row][k..k+7]
  bf16x8 whf[3][4], wif[3][4];
  #pragma unroll
  for (int g = 0; g < 3; ++g) {
    const int grow = g * Hn + j0 + arow;
    #pragma unroll
    for (int s = 0; s < 4; ++s) {
      const int kk = kb + s * 32 + koff;
      const float* ph = w_hh + (size_t)grow * Dn + kk;
      const float* pi = w_ih + (size_t)grow * Dn + kk;
      bf16x8 a, b;
      #pragma unroll
      for (int i = 0; i < 8; ++i) { a[i] = (short)f2bf(ph[i]); b[i] = (short)f2bf(pi[i]); }
      whf[g][s] = a; wif[g][s] = b;
    }
  }

  // ---- per-thread epilogue constants: thread tid -> (batch bq, col jg) ----
  const int bq = tid >> 4;
  const int jj = tid & 15;
  const int jg = j0 + jj;
  const float bias_r  = b_ih[jg]          + b_hh[jg];
  const float bias_z  = b_ih[Hn + jg]     + b_hh[Hn + jg];
  const float bias_nx = b_ih[2 * Hn + jg];
  const float bias_nh = b_hh[2 * Hn + jg];
  const int   start_g = start[bq];
  const int   start_a = start[arow];

  float h_own = 0.f;                      // this thread's h[bq][jg], kept in f32
  __shared__ float red[4][4][NTHREADS];   // [tile r/z/nx/nh][wave][pos]

  const float* xrow   = x + (size_t)arow * Tn * Dn + kb + koff;
  const float* xres_p = x + (size_t)bq   * Tn * Dn + jg;

  #pragma unroll 1
  for (int t = 0; t < Tn; ++t) {
    // -------- phase A: input projection (independent of other WGs; overlaps barrier) --------
    const float* xt = xrow + (size_t)t * Dn;
    f32x4 xa[4][2];
    #pragma unroll
    for (int s = 0; s < 4; ++s) {
      xa[s][0] = *(const f32x4*)(xt + s * 32);
      xa[s][1] = *(const f32x4*)(xt + s * 32 + 4);
    }
    const float xres = xres_p[(size_t)t * Dn];
    bf16x8 xf[4];
    #pragma unroll
    for (int s = 0; s < 4; ++s) {
      bf16x8 v;
      #pragma unroll
      for (int i = 0; i < 4; ++i) {
        v[i]     = (short)f2bf(xa[s][0][i]);
        v[4 + i] = (short)f2bf(xa[s][1][i]);
      }
      xf[s] = v;
    }
    f32x4 ar = {0,0,0,0}, az = {0,0,0,0}, anx = {0,0,0,0}, anh = {0,0,0,0};
    #pragma unroll
    for (int s = 0; s < 4; ++s) {
      ar  = __builtin_amdgcn_mfma_f32_16x16x32_bf16(xf[s], wif[0][s], ar,  0, 0, 0);
      az  = __builtin_amdgcn_mfma_f32_16x16x32_bf16(xf[s], wif[1][s], az,  0, 0, 0);
      anx = __builtin_amdgcn_mfma_f32_16x16x32_bf16(xf[s], wif[2][s], anx, 0, 0, 0);
    }

    // -------- phase B: wait until all WGs published h(t) --------
    if (t > 0) {
      if (tid == 0) {
        const unsigned target = (unsigned)NWG * (unsigned)t;
        while (__hip_atomic_load(counter, __ATOMIC_RELAXED, __HIP_MEMORY_SCOPE_AGENT) < target)
          __builtin_amdgcn_s_sleep(1);
        __threadfence();   // agent acquire: invalidate L1/L2 so h_ex loads are fresh
      }
      __syncthreads();
    }

    // -------- phase C: hidden projection (mask applied at A-load) --------
    const bool am = (start_a < t);
    const unsigned short* hbase =
        h_ex + (size_t)(t & 1) * (Bn * Hn) + (size_t)arow * Hn + kb + koff;
    #pragma unroll
    for (int s = 0; s < 4; ++s) {
      union { uint4 u; bf16x8 v; } hw;
      hw.u = *(const uint4*)(hbase + s * 32);
      if (!am) hw.u = make_uint4(0, 0, 0, 0);
      ar  = __builtin_amdgcn_mfma_f32_16x16x32_bf16(hw.v, whf[0][s], ar,  0, 0, 0);
      az  = __builtin_amdgcn_mfma_f32_16x16x32_bf16(hw.v, whf[1][s], az,  0, 0, 0);
      anh = __builtin_amdgcn_mfma_f32_16x16x32_bf16(hw.v, whf[2][s], anh, 0, 0, 0);
    }

    // -------- phase D: cross-wave reduce + gates + state update --------
    #pragma unroll
    for (int i = 0; i < 4; ++i) {
      const int pos = (((lane >> 4) * 4) + i) * 16 + arow;  // C layout: row=(l>>4)*4+i, col=l&15
      red[0][wv][pos] = ar[i];
      red[1][wv][pos] = az[i];
      red[2][wv][pos] = anx[i];
      red[3][wv][pos] = anh[i];
    }
    __syncthreads();
    float sr = bias_r, sz = bias_z, snx = bias_nx, snh = bias_nh;
    #pragma unroll
    for (int w2 = 0; w2 < 4; ++w2) {
      sr  += red[0][w2][tid];
      sz  += red[1][w2][tid];
      snx += red[2][w2][tid];
      snh += red[3][w2][tid];
    }
    const float r  = 1.f / (1.f + __expf(-sr));
    const float z  = 1.f / (1.f + __expf(-sz));
    const float n  = tanhf(snx + r * snh);
    const float hm = (start_g < t) ? h_own : 0.f;
    const float hn = (1.f - z) * n + z * hm;
    h_own = hn;
    const size_t oo = ((size_t)bq * Tn + t) * Hn + jg;
    out[oo] = xres + hn;                         // residual output
    out[(size_t)Bn * Tn * Hn + oo] = hn;         // hidden output
    h_ex[(size_t)((t + 1) & 1) * (Bn * Hn) + (size_t)bq * Hn + jg] = f2bf(hn);

    // -------- phase E: publish h(t+1) --------
    __syncthreads();   // drains every thread's stores (vmcnt(0) before s_barrier)
    if (tid == 0)
      __hip_atomic_fetch_add(counter, 1u, __ATOMIC_RELEASE, __HIP_MEMORY_SCOPE_AGENT);
  }
}

extern "C" void kernel_launch(void* const* d_in, const int* in_sizes, int n_in,
                              void* d_out, int out_size, void* d_ws, size_t ws_size,
                              hipStream_t stream) {
  const float* x     = (const float*)d_in[0];
  const int*   start = (const int*)d_in[1];
  const float* w_ih  = (const float*)d_in[2];
  const float* w_hh  = (const float*)d_in[3];
  const float* b_ih  = (const float*)d_in[4];
  const float* b_hh  = (const float*)d_in[5];
  float* out = (float*)d_out;

  // ws layout: [0,256) barrier counter (+pad), [256, 256+32KB) ping-pong h (bf16)
  unsigned int*   counter = (unsigned int*)d_ws;
  unsigned short* h_ex    = (unsigned short*)((char*)d_ws + 256);

  hipMemsetAsync(d_ws, 0, 256, stream);  // reset barrier counter each launch (graph-safe)
  hipLaunchKernelGGL(gru_scan, dim3(NWG), dim3(NTHREADS), 0, stream,
                     x, start, w_ih, w_hh, b_ih, b_hh, out, h_ex, counter);
}